// Round 2
// baseline (4271.402 us; speedup 1.0000x reference)
//
#include <hip/hip_runtime.h>

static constexpr int   NB     = 4;     // batches
static constexpr int   PP     = 1024;  // points per side
static constexpr int   DD     = 16;    // feature dim
static constexpr float EPSV   = 0.1f;
static constexpr float IEPS   = 10.0f; // 1/eps
static constexpr int   MAXIT  = 100;
static constexpr float THRESHV = 0.1f;

static constexpr int NBLK  = 256;              // 1 block/CU guaranteed resident
static constexpr int NTHR  = 512;              // 8 waves
static constexpr int RPB   = 16;               // rows (and cols) per block
static constexpr int NERRS = 64;               // err slots per iteration

// workspace layout (floats)
static constexpr int BAR_OFF = 0;              // [0]=cnt(u32) [1]=gen(u32)
static constexpr int U_OFF   = 16;
static constexpr int V_OFF   = U_OFF + NB * PP;          // 4112
static constexpr int E_OFF   = V_OFF + NB * PP;          // 8208
static constexpr int CP_OFF  = E_OFF + MAXIT * NERRS;    // 14608
static constexpr int WS_FLOATS = CP_OFF + NB * 64;       // 14864
static constexpr size_t WS_BYTES = (size_t)WS_FLOATS * 4;

// Generation-based grid barrier. Requires all NBLK blocks co-resident
// (true: 256 blocks, <=1 block/CU resources). Cumulative counter -> no reset race.
__device__ __forceinline__ void gbar(unsigned* cnt, unsigned* gen, unsigned& lgen) {
    __syncthreads();
    if (threadIdx.x == 0) {
        unsigned g = lgen;
        __threadfence();   // release: agent-scope (wb L2 for cross-XCD visibility)
        unsigned arrived =
            __hip_atomic_fetch_add(cnt, 1u, __ATOMIC_RELAXED, __HIP_MEMORY_SCOPE_AGENT) + 1u;
        if (arrived == (unsigned)NBLK * (g + 1u)) {
            __hip_atomic_store(gen, g + 1u, __ATOMIC_RELEASE, __HIP_MEMORY_SCOPE_AGENT);
        }
        while (__hip_atomic_load(gen, __ATOMIC_RELAXED, __HIP_MEMORY_SCOPE_AGENT) < g + 1u) {
            __builtin_amdgcn_s_sleep(1);
        }
        __threadfence();   // acquire: invalidate L1/L2 stale lines
        lgen = g + 1u;
    }
    __syncthreads();
}

__global__ __launch_bounds__(NTHR, 2)
void sinkhorn_kernel(const float* __restrict__ x, const float* __restrict__ y,
                     const float* __restrict__ wx, const float* __restrict__ wy,
                     float* __restrict__ out, float* __restrict__ ws)
{
    __shared__ float rt[RPB * PP];   // row tile: rt[r*1024 + j] = C[n][i0+r][j]  (64 KB)

    unsigned* bar_cnt = (unsigned*)(ws + BAR_OFF);
    unsigned* bar_gen = (unsigned*)(ws + BAR_OFF) + 1;
    float* u_ws  = ws + U_OFF;
    float* v_ws  = ws + V_OFF;
    float* e_ws  = ws + E_OFF;
    float* cp_ws = ws + CP_OFF;

    float* out_cost = out;
    float* out_pi   = out + NB;
    float* out_C    = out + NB + (size_t)NB * PP * PP;

    const int b  = blockIdx.x;
    const int n  = b >> 6;            // 64 blocks per batch
    const int i0 = (b & 63) * RPB;    // first row
    const int j0 = i0;                // first col
    const int w  = threadIdx.x >> 6;  // wave 0..7
    const int l  = threadIdx.x & 63;  // lane

    unsigned lgen = 0;

    // ---------------- stage A: cost matrix (16 rows -> LDS + global) ----------------
    float4 xr[2][4];
    #pragma unroll
    for (int rr = 0; rr < 2; ++rr) {
        const float4* xp = (const float4*)(x + ((size_t)n * PP + (i0 + 2 * w + rr)) * DD);
        #pragma unroll
        for (int q = 0; q < 4; ++q) xr[rr][q] = xp[q];
    }
    #pragma unroll 4
    for (int k = 0; k < 16; ++k) {
        int j = l + 64 * k;
        const float4* yp = (const float4*)(y + ((size_t)n * PP + j) * DD);
        float4 y0 = yp[0], y1 = yp[1], y2 = yp[2], y3 = yp[3];
        #pragma unroll
        for (int rr = 0; rr < 2; ++rr) {
            float c = fabsf(xr[rr][0].x - y0.x) + fabsf(xr[rr][0].y - y0.y)
                    + fabsf(xr[rr][0].z - y0.z) + fabsf(xr[rr][0].w - y0.w)
                    + fabsf(xr[rr][1].x - y1.x) + fabsf(xr[rr][1].y - y1.y)
                    + fabsf(xr[rr][1].z - y1.z) + fabsf(xr[rr][1].w - y1.w)
                    + fabsf(xr[rr][2].x - y2.x) + fabsf(xr[rr][2].y - y2.y)
                    + fabsf(xr[rr][2].z - y2.z) + fabsf(xr[rr][2].w - y2.w)
                    + fabsf(xr[rr][3].x - y3.x) + fabsf(xr[rr][3].y - y3.y)
                    + fabsf(xr[rr][3].z - y3.z) + fabsf(xr[rr][3].w - y3.w);
            rt[(2 * w + rr) * PP + j] = c;
            out_C[((size_t)n * PP + (i0 + 2 * w + rr)) * PP + j] = c;
        }
    }

    gbar(bar_cnt, bar_gen, lgen);   // C complete device-wide; ws already zeroed by memset

    // ---------------- stage B: this block's 16 C-columns -> registers ----------------
    // wave w owns cols j0+2w, j0+2w+1; lane l holds rows l+64k, k=0..15
    float2 c2[16];
    const float* Cb = out_C + (size_t)n * PP * PP;
    #pragma unroll
    for (int k = 0; k < 16; ++k)
        c2[k] = *(const float2*)(Cb + (size_t)(l + 64 * k) * PP + (j0 + 2 * w));

    float u_loc[2], lmu[2], lnu[2];
    #pragma unroll
    for (int rr = 0; rr < 2; ++rr) {
        u_loc[rr] = 0.f;
        lmu[rr] = __logf(wx[n * PP + i0 + 2 * w + rr] + 1e-8f);
        lnu[rr] = __logf(wy[n * PP + j0 + 2 * w + rr] + 1e-8f);
    }

    // ---------------- Sinkhorn loop ----------------
    bool done = false;
    for (int t = 0; t < MAXIT; ++t) {
        // u-phase: u_new[i] = eps*log_mu[i] - eps*LSE_j((v_j - C_ij)/eps)
        float vv[16];
        #pragma unroll
        for (int k = 0; k < 16; ++k) vv[k] = v_ws[n * PP + l + 64 * k];
        float werr = 0.f;
        #pragma unroll
        for (int rr = 0; rr < 2; ++rr) {
            int r = 2 * w + rr;
            float tt[16], m = -3.4e38f;
            #pragma unroll
            for (int k = 0; k < 16; ++k) {
                tt[k] = vv[k] - rt[r * PP + l + 64 * k];
                m = fmaxf(m, tt[k]);
            }
            #pragma unroll
            for (int off = 32; off >= 1; off >>= 1) m = fmaxf(m, __shfl_xor(m, off));
            float s = 0.f;
            #pragma unroll
            for (int k = 0; k < 16; ++k) s += __expf((tt[k] - m) * IEPS);
            #pragma unroll
            for (int off = 32; off >= 1; off >>= 1) s += __shfl_xor(s, off);
            float unew = EPSV * lmu[rr] - (m + EPSV * __logf(s));
            werr += fabsf(unew - u_loc[rr]);
            u_loc[rr] = unew;
            if (l == 0) u_ws[n * PP + i0 + r] = unew;
        }
        if (l == 0) atomicAdd(&e_ws[t * NERRS + (b & 63)], werr);

        gbar(bar_cnt, bar_gen, lgen);   // u_new + err visible

        // v-phase: v_new[j] = eps*log_nu[j] - eps*LSE_i((u_i - C_ij)/eps)
        float uu[16];
        #pragma unroll
        for (int k = 0; k < 16; ++k) uu[k] = u_ws[n * PP + l + 64 * k];
        #pragma unroll
        for (int c = 0; c < 2; ++c) {
            float tt[16], m = -3.4e38f;
            #pragma unroll
            for (int k = 0; k < 16; ++k) {
                tt[k] = uu[k] - (c ? c2[k].y : c2[k].x);
                m = fmaxf(m, tt[k]);
            }
            #pragma unroll
            for (int off = 32; off >= 1; off >>= 1) m = fmaxf(m, __shfl_xor(m, off));
            float s = 0.f;
            #pragma unroll
            for (int k = 0; k < 16; ++k) s += __expf((tt[k] - m) * IEPS);
            #pragma unroll
            for (int off = 32; off >= 1; off >>= 1) s += __shfl_xor(s, off);
            float vnew = EPSV * lnu[c] - (m + EPSV * __logf(s));
            if (l == 0) v_ws[n * PP + j0 + 2 * w + c] = vnew;
        }

        // convergence (uniform): lane l reads slot l, butterfly -> identical in all lanes
        float e = e_ws[t * NERRS + l];
        #pragma unroll
        for (int off = 32; off >= 1; off >>= 1) e += __shfl_xor(e, off);
        done = (e < THRESHV * (float)NB);   // mean over batches < THRESH

        gbar(bar_cnt, bar_gen, lgen);   // v_new visible
        if (done) break;
    }

    // ---------------- epilogue: pi = exp(M(u,v)), cost = sum(pi*C) ----------------
    float vv[16];
    #pragma unroll
    for (int k = 0; k < 16; ++k) vv[k] = v_ws[n * PP + l + 64 * k];
    float cacc = 0.f;
    #pragma unroll
    for (int rr = 0; rr < 2; ++rr) {
        int r = 2 * w + rr;
        float un = u_loc[rr];
        #pragma unroll
        for (int k = 0; k < 16; ++k) {
            int j = l + 64 * k;
            float cij = rt[r * PP + j];
            float p = __expf((un + vv[k] - cij) * IEPS);
            out_pi[((size_t)n * PP + (i0 + r)) * PP + j] = p;
            cacc += p * cij;
        }
    }
    #pragma unroll
    for (int off = 32; off >= 1; off >>= 1) cacc += __shfl_xor(cacc, off);
    if (l == 0) atomicAdd(&cp_ws[n * 64 + (b & 63)], cacc);

    gbar(bar_cnt, bar_gen, lgen);   // cost partials visible

    if (b == 0 && w < NB) {
        float e = cp_ws[w * 64 + l];
        #pragma unroll
        for (int off = 32; off >= 1; off >>= 1) e += __shfl_xor(e, off);
        if (l == 0) out_cost[w] = e;
    }
}

extern "C" void kernel_launch(void* const* d_in, const int* in_sizes, int n_in,
                              void* d_out, int out_size, void* d_ws, size_t ws_size,
                              hipStream_t stream) {
    const float* x  = (const float*)d_in[0];
    const float* y  = (const float*)d_in[1];
    const float* wx = (const float*)d_in[2];
    const float* wy = (const float*)d_in[3];
    float* out = (float*)d_out;
    float* ws  = (float*)d_ws;

    // zero barrier/u/v/err/cost-partials (ws is poisoned 0xAA before every launch)
    hipMemsetAsync(d_ws, 0, WS_BYTES, stream);

    hipLaunchKernelGGL(sinkhorn_kernel, dim3(NBLK), dim3(NTHR), 0, stream,
                       x, y, wx, wy, out, ws);
}

// Round 3
// 2326.104 us; speedup vs baseline: 1.8363x; 1.8363x over previous
//
#include <hip/hip_runtime.h>

static constexpr int   NB     = 4;     // batches
static constexpr int   PP     = 1024;  // points per side
static constexpr int   DD     = 16;    // feature dim
static constexpr float EPSV   = 0.1f;
static constexpr float IEPS   = 10.0f; // 1/eps
static constexpr int   MAXIT  = 100;
static constexpr float THRESHV = 0.1f;

static constexpr int NBLK   = 256;     // 1 block/CU, all co-resident
static constexpr int NTHR   = 512;     // 8 waves
static constexpr int NERRS  = 64;      // err slots per iteration
static constexpr int NLEAF  = 16;      // barrier tree leaves (16 blocks each)

// workspace layout (floats). Barrier u32s live in ws[0..287]:
//   leaf i -> u32 index i*16 (64 B apart), root -> 256, gen -> 272
static constexpr int U_OFF = 320;
static constexpr int V_OFF = U_OFF + NB * PP;           // +4096
static constexpr int E_OFF = V_OFF + NB * PP;           // +4096
static constexpr int WS_FLOATS = E_OFF + MAXIT * NERRS; // +6400
static constexpr size_t WS_BYTES = (size_t)WS_FLOATS * 4;

__device__ __forceinline__ float aload(const float* p) {
    return __hip_atomic_load(p, __ATOMIC_RELAXED, __HIP_MEMORY_SCOPE_AGENT);
}
__device__ __forceinline__ void astore(float* p, float v) {
    __hip_atomic_store(p, v, __ATOMIC_RELAXED, __HIP_MEMORY_SCOPE_AGENT);
}

// Fence-free tree barrier. Data ordering contract: all inter-block data is
// written with sc0/sc1 write-through atomic stores; __syncthreads() drains
// each wave's vmcnt before s_barrier, so data is at the coherence point
// before thread 0's arrival add. Readers use sc0/sc1 atomic loads -> fresh.
__device__ __forceinline__ void gbar(unsigned* bar, unsigned& lgen) {
    __syncthreads();
    if (threadIdx.x == 0) {
        unsigned g = lgen + 1u;
        unsigned* leaf = bar + (blockIdx.x & (NLEAF - 1)) * 16;
        unsigned a = __hip_atomic_fetch_add(leaf, 1u, __ATOMIC_RELAXED,
                                            __HIP_MEMORY_SCOPE_AGENT) + 1u;
        if (a == (unsigned)(NBLK / NLEAF) * g) {          // last in leaf
            unsigned r = __hip_atomic_fetch_add(bar + 256, 1u, __ATOMIC_RELAXED,
                                                __HIP_MEMORY_SCOPE_AGENT) + 1u;
            if (r == (unsigned)NLEAF * g) {               // last leaf
                __hip_atomic_store(bar + 272, g, __ATOMIC_RELAXED,
                                   __HIP_MEMORY_SCOPE_AGENT);
            }
        }
        while (__hip_atomic_load(bar + 272, __ATOMIC_RELAXED,
                                 __HIP_MEMORY_SCOPE_AGENT) < g) {
            __builtin_amdgcn_s_sleep(1);
        }
        lgen = g;
    }
    __syncthreads();
}

__global__ __launch_bounds__(NTHR, 2)
void sinkhorn_kernel(const float* __restrict__ x, const float* __restrict__ y,
                     const float* __restrict__ wx, const float* __restrict__ wy,
                     float* __restrict__ out, float* __restrict__ ws)
{
    __shared__ float rt[16 * PP];    // row tile: C[i0+r][0..1023]   (64 KB)
    __shared__ float sbuf[PP];       // u/v broadcast buffer          (4 KB)

    unsigned* bar = (unsigned*)ws;
    float* u_ws = ws + U_OFF;
    float* v_ws = ws + V_OFF;
    float* e_ws = ws + E_OFF;

    float* out_cost = out;
    float* out_pi   = out + NB;
    float* out_C    = out + NB + (size_t)NB * PP * PP;

    const int b  = blockIdx.x;
    const int n  = b >> 6;            // 64 blocks per batch
    const int i0 = (b & 63) * 16;     // first row of this block
    const int j0 = i0;                // first col of this block
    const int w  = threadIdx.x >> 6;  // wave 0..7
    const int l  = threadIdx.x & 63;  // lane

    unsigned lgen = 0;

    // ---------------- stage A: 16 C-rows -> LDS + global ----------------
    float4 xr[2][4];
    #pragma unroll
    for (int rr = 0; rr < 2; ++rr) {
        const float4* xp = (const float4*)(x + ((size_t)n * PP + (i0 + 2 * w + rr)) * DD);
        #pragma unroll
        for (int q = 0; q < 4; ++q) xr[rr][q] = xp[q];
    }
    #pragma unroll 4
    for (int k = 0; k < 16; ++k) {
        int j = l + 64 * k;
        const float4* yp = (const float4*)(y + ((size_t)n * PP + j) * DD);
        float4 y0 = yp[0], y1 = yp[1], y2 = yp[2], y3 = yp[3];
        #pragma unroll
        for (int rr = 0; rr < 2; ++rr) {
            float c = fabsf(xr[rr][0].x - y0.x) + fabsf(xr[rr][0].y - y0.y)
                    + fabsf(xr[rr][0].z - y0.z) + fabsf(xr[rr][0].w - y0.w)
                    + fabsf(xr[rr][1].x - y1.x) + fabsf(xr[rr][1].y - y1.y)
                    + fabsf(xr[rr][1].z - y1.z) + fabsf(xr[rr][1].w - y1.w)
                    + fabsf(xr[rr][2].x - y2.x) + fabsf(xr[rr][2].y - y2.y)
                    + fabsf(xr[rr][2].z - y2.z) + fabsf(xr[rr][2].w - y2.w)
                    + fabsf(xr[rr][3].x - y3.x) + fabsf(xr[rr][3].y - y3.y)
                    + fabsf(xr[rr][3].z - y3.z) + fabsf(xr[rr][3].w - y3.w);
            rt[(2 * w + rr) * PP + j] = c;
            out_C[((size_t)n * PP + (i0 + 2 * w + rr)) * PP + j] = c;
        }
    }

    // ---------------- stage B: 16 C-cols recomputed into registers ----------------
    // wave w owns cols j0+2w, j0+2w+1; lane l holds rows l+64k, k=0..15.
    // Recomputed locally from x,y -> no cross-block dependency, no barrier needed.
    float4 yc[2][4];
    #pragma unroll
    for (int c = 0; c < 2; ++c) {
        const float4* yp = (const float4*)(y + ((size_t)n * PP + (j0 + 2 * w + c)) * DD);
        #pragma unroll
        for (int q = 0; q < 4; ++q) yc[c][q] = yp[q];
    }
    float2 c2[16];
    #pragma unroll 4
    for (int k = 0; k < 16; ++k) {
        const float4* xp = (const float4*)(x + ((size_t)n * PP + (l + 64 * k)) * DD);
        float4 x0 = xp[0], x1 = xp[1], x2 = xp[2], x3 = xp[3];
        float cc[2];
        #pragma unroll
        for (int c = 0; c < 2; ++c) {
            cc[c] = fabsf(x0.x - yc[c][0].x) + fabsf(x0.y - yc[c][0].y)
                  + fabsf(x0.z - yc[c][0].z) + fabsf(x0.w - yc[c][0].w)
                  + fabsf(x1.x - yc[c][1].x) + fabsf(x1.y - yc[c][1].y)
                  + fabsf(x1.z - yc[c][1].z) + fabsf(x1.w - yc[c][1].w)
                  + fabsf(x2.x - yc[c][2].x) + fabsf(x2.y - yc[c][2].y)
                  + fabsf(x2.z - yc[c][2].z) + fabsf(x2.w - yc[c][2].w)
                  + fabsf(x3.x - yc[c][3].x) + fabsf(x3.y - yc[c][3].y)
                  + fabsf(x3.z - yc[c][3].z) + fabsf(x3.w - yc[c][3].w);
        }
        c2[k] = make_float2(cc[0], cc[1]);
    }

    float u_loc[2], lmu[2], lnu[2];
    #pragma unroll
    for (int rr = 0; rr < 2; ++rr) {
        u_loc[rr] = 0.f;
        lmu[rr] = __logf(wx[n * PP + i0 + 2 * w + rr] + 1e-8f);
        lnu[rr] = __logf(wy[n * PP + j0 + 2 * w + rr] + 1e-8f);
    }

    // ---------------- Sinkhorn loop: 2 barriers per iteration ----------------
    bool done = false;
    for (int t = 0; t < MAXIT; ++t) {
        // u-phase: u_new[i] = eps*log_mu[i] - eps*LSE_j((v_j - C_ij)/eps)
        for (int idx = threadIdx.x; idx < PP; idx += NTHR)
            sbuf[idx] = aload(&v_ws[n * PP + idx]);     // iter 0: zeros from memset
        __syncthreads();

        float vv[16];
        #pragma unroll
        for (int k = 0; k < 16; ++k) vv[k] = sbuf[l + 64 * k];
        float werr = 0.f;
        #pragma unroll
        for (int rr = 0; rr < 2; ++rr) {
            int r = 2 * w + rr;
            float tt[16], m = -3.4e38f;
            #pragma unroll
            for (int k = 0; k < 16; ++k) {
                tt[k] = vv[k] - rt[r * PP + l + 64 * k];
                m = fmaxf(m, tt[k]);
            }
            #pragma unroll
            for (int off = 32; off >= 1; off >>= 1) m = fmaxf(m, __shfl_xor(m, off));
            float s = 0.f;
            #pragma unroll
            for (int k = 0; k < 16; ++k) s += __expf((tt[k] - m) * IEPS);
            #pragma unroll
            for (int off = 32; off >= 1; off >>= 1) s += __shfl_xor(s, off);
            float unew = EPSV * lmu[rr] - (m + EPSV * __logf(s));
            werr += fabsf(unew - u_loc[rr]);
            u_loc[rr] = unew;
            if (l == 0) astore(&u_ws[n * PP + i0 + r], unew);
        }
        if (l == 0) atomicAdd(&e_ws[t * NERRS + (b & 63)], werr);

        gbar(bar, lgen);   // u_new + err visible

        // v-phase: v_new[j] = eps*log_nu[j] - eps*LSE_i((u_i - C_ij)/eps)
        for (int idx = threadIdx.x; idx < PP; idx += NTHR)
            sbuf[idx] = aload(&u_ws[n * PP + idx]);
        __syncthreads();

        float uu[16];
        #pragma unroll
        for (int k = 0; k < 16; ++k) uu[k] = sbuf[l + 64 * k];
        #pragma unroll
        for (int c = 0; c < 2; ++c) {
            float tt[16], m = -3.4e38f;
            #pragma unroll
            for (int k = 0; k < 16; ++k) {
                tt[k] = uu[k] - (c ? c2[k].y : c2[k].x);
                m = fmaxf(m, tt[k]);
            }
            #pragma unroll
            for (int off = 32; off >= 1; off >>= 1) m = fmaxf(m, __shfl_xor(m, off));
            float s = 0.f;
            #pragma unroll
            for (int k = 0; k < 16; ++k) s += __expf((tt[k] - m) * IEPS);
            #pragma unroll
            for (int off = 32; off >= 1; off >>= 1) s += __shfl_xor(s, off);
            float vnew = EPSV * lnu[c] - (m + EPSV * __logf(s));
            if (l == 0) astore(&v_ws[n * PP + j0 + 2 * w + c], vnew);
        }

        // convergence: lane l reads err slot l, butterfly -> uniform everywhere
        float e = aload(&e_ws[t * NERRS + l]);
        #pragma unroll
        for (int off = 32; off >= 1; off >>= 1) e += __shfl_xor(e, off);
        done = (e < THRESHV * (float)NB);   // mean over batches < THRESH

        gbar(bar, lgen);   // v_new visible; all blocks exit together
        if (done) break;
    }

    // ---------------- epilogue: pi = exp(M(u,v)), cost = sum(pi*C) ----------------
    for (int idx = threadIdx.x; idx < PP; idx += NTHR)
        sbuf[idx] = aload(&v_ws[n * PP + idx]);
    __syncthreads();

    float vv[16];
    #pragma unroll
    for (int k = 0; k < 16; ++k) vv[k] = sbuf[l + 64 * k];
    float cacc = 0.f;
    #pragma unroll
    for (int rr = 0; rr < 2; ++rr) {
        int r = 2 * w + rr;
        float un = u_loc[rr];
        #pragma unroll
        for (int k = 0; k < 16; ++k) {
            int j = l + 64 * k;
            float cij = rt[r * PP + j];
            float p = __expf((un + vv[k] - cij) * IEPS);
            out_pi[((size_t)n * PP + (i0 + r)) * PP + j] = p;
            cacc += p * cij;
        }
    }
    #pragma unroll
    for (int off = 32; off >= 1; off >>= 1) cacc += __shfl_xor(cacc, off);
    if (l == 0) atomicAdd(&out_cost[n], cacc);   // out_cost zeroed by memset
}

extern "C" void kernel_launch(void* const* d_in, const int* in_sizes, int n_in,
                              void* d_out, int out_size, void* d_ws, size_t ws_size,
                              hipStream_t stream) {
    const float* x  = (const float*)d_in[0];
    const float* y  = (const float*)d_in[1];
    const float* wx = (const float*)d_in[2];
    const float* wy = (const float*)d_in[3];
    float* out = (float*)d_out;
    float* ws  = (float*)d_ws;

    hipMemsetAsync(d_ws, 0, WS_BYTES, stream);        // barrier/u/v/err
    hipMemsetAsync(d_out, 0, NB * sizeof(float), stream); // cost accumulators

    hipLaunchKernelGGL(sinkhorn_kernel, dim3(NBLK), dim3(NTHR), 0, stream,
                       x, y, wx, wy, out, ws);
}

// Round 4
// 1566.067 us; speedup vs baseline: 2.7275x; 1.4853x over previous
//
#include <hip/hip_runtime.h>

static constexpr int   NB      = 4;     // batches
static constexpr int   PP      = 1024;  // points per side
static constexpr int   DD      = 16;    // feature dim
static constexpr float EPSV    = 0.1f;
static constexpr float IEPS    = 10.0f; // 1/eps
static constexpr int   MAXIT   = 100;
static constexpr float THRESHV = 0.1f;

static constexpr int NBLK = 256;        // 64 blocks per batch, all co-resident
static constexpr int GPB  = 64;         // blocks per group (batch)
static constexpr int NTHR = 512;        // 8 waves

// ---- workspace layout ----
// u32 region (barrier lines, 64 B = 16 u32 apart):
//   group counter n       : u32 idx n*16              (n<4)
//   group flags  (n,f)    : u32 idx 64 + n*128 + f*16 (f<8)
//   final counter         : u32 idx 576
//   final flags  f        : u32 idx 592 + f*16        (f<16)
// float region:
//   e_ws[(n*MAXIT+t)*8+s] : float idx 1024 + ...      (s<8)
static constexpr int E_OFF     = 1024;
static constexpr int WS_FLOATS = E_OFF + NB * MAXIT * 8;   // 4224
static constexpr size_t WS_BYTES = (size_t)WS_FLOATS * 4;

// snapshots live in the out_C region (scratch until epilogue):
//   per batch base sc = out_C + n*PP*PP (1M floats; snapshots use 232K)
//   u_snap(t) = sc + t*PP ; v_snap(t) = sc + 131072 + t*PP
static constexpr int VSNAP_OFF = 131072;

__device__ __forceinline__ float aload(const float* p) {
    return __hip_atomic_load(p, __ATOMIC_RELAXED, __HIP_MEMORY_SCOPE_AGENT);
}
__device__ __forceinline__ void astore(float* p, float v) {
    __hip_atomic_store(p, v, __ATOMIC_RELAXED, __HIP_MEMORY_SCOPE_AGENT);
}

// Fence-free barrier: flat arrival counter + distributed notify flags.
// Data contract (proven in R3): inter-block data moves via agent-scope
// relaxed atomics (write-through); __syncthreads() drains vmcnt before
// s_barrier, so data is at the coherence point before the arrival add.
__device__ __forceinline__ void barrier_wait(unsigned* cnt, unsigned* flags,
                                             int nflags, int myflag,
                                             unsigned total, unsigned g) {
    __syncthreads();
    if (threadIdx.x == 0) {
        unsigned a = __hip_atomic_fetch_add(cnt, 1u, __ATOMIC_RELAXED,
                                            __HIP_MEMORY_SCOPE_AGENT) + 1u;
        if (a == total * g) {
            for (int f = 0; f < nflags; ++f)
                __hip_atomic_store(flags + f * 16, g, __ATOMIC_RELAXED,
                                   __HIP_MEMORY_SCOPE_AGENT);
        }
        while (__hip_atomic_load(flags + myflag * 16, __ATOMIC_RELAXED,
                                 __HIP_MEMORY_SCOPE_AGENT) < g) {
            __builtin_amdgcn_s_sleep(2);
        }
    }
    __syncthreads();
}

__global__ __launch_bounds__(NTHR, 2)
void sinkhorn_kernel(const float* __restrict__ x, const float* __restrict__ y,
                     const float* __restrict__ wx, const float* __restrict__ wy,
                     float* __restrict__ out, float* __restrict__ ws)
{
    __shared__ float rt[16 * PP];    // C rows tile (64 KB), live whole kernel
    __shared__ float sbuf[PP];       // u/v broadcast buffer (4 KB)
    __shared__ float cred[8];        // cost partials per wave
    __shared__ int   Ts;             // chosen iteration T

    unsigned* ws32 = (unsigned*)ws;
    float* e_ws = ws + E_OFF;

    float* out_cost = out;
    float* out_pi   = out + NB;
    float* out_C    = out + NB + (size_t)NB * PP * PP;

    const int b  = blockIdx.x;
    const int n  = b >> 6;            // batch
    const int g  = b & 63;            // block within group
    const int i0 = g * 16;            // first row (and col) of this block
    const int w  = threadIdx.x >> 6;  // wave 0..7
    const int l  = threadIdx.x & 63;  // lane

    unsigned* grp_cnt   = ws32 + n * 16;
    unsigned* grp_flags = ws32 + 64 + n * 128;
    const int grp_myflag = g >> 3;
    unsigned* fin_cnt   = ws32 + 576;
    unsigned* fin_flags = ws32 + 592;

    float* sc = out_C + (size_t)n * PP * PP;   // this batch's snapshot scratch

    // ---------------- stage A: 16 C-rows -> LDS only ----------------
    float4 xr[2][4];
    #pragma unroll
    for (int rr = 0; rr < 2; ++rr) {
        const float4* xp = (const float4*)(x + ((size_t)n * PP + (i0 + 2 * w + rr)) * DD);
        #pragma unroll
        for (int q = 0; q < 4; ++q) xr[rr][q] = xp[q];
    }
    #pragma unroll 4
    for (int k = 0; k < 16; ++k) {
        int j = l + 64 * k;
        const float4* yp = (const float4*)(y + ((size_t)n * PP + j) * DD);
        float4 y0 = yp[0], y1 = yp[1], y2 = yp[2], y3 = yp[3];
        #pragma unroll
        for (int rr = 0; rr < 2; ++rr) {
            float c = fabsf(xr[rr][0].x - y0.x) + fabsf(xr[rr][0].y - y0.y)
                    + fabsf(xr[rr][0].z - y0.z) + fabsf(xr[rr][0].w - y0.w)
                    + fabsf(xr[rr][1].x - y1.x) + fabsf(xr[rr][1].y - y1.y)
                    + fabsf(xr[rr][1].z - y1.z) + fabsf(xr[rr][1].w - y1.w)
                    + fabsf(xr[rr][2].x - y2.x) + fabsf(xr[rr][2].y - y2.y)
                    + fabsf(xr[rr][2].z - y2.z) + fabsf(xr[rr][2].w - y2.w)
                    + fabsf(xr[rr][3].x - y3.x) + fabsf(xr[rr][3].y - y3.y)
                    + fabsf(xr[rr][3].z - y3.z) + fabsf(xr[rr][3].w - y3.w);
            rt[(2 * w + rr) * PP + j] = c;
        }
    }

    // ---------------- stage B: 16 C-cols recomputed into registers ----------------
    float4 yc[2][4];
    #pragma unroll
    for (int c = 0; c < 2; ++c) {
        const float4* yp = (const float4*)(y + ((size_t)n * PP + (i0 + 2 * w + c)) * DD);
        #pragma unroll
        for (int q = 0; q < 4; ++q) yc[c][q] = yp[q];
    }
    float2 c2[16];
    #pragma unroll 4
    for (int k = 0; k < 16; ++k) {
        const float4* xp = (const float4*)(x + ((size_t)n * PP + (l + 64 * k)) * DD);
        float4 x0 = xp[0], x1 = xp[1], x2 = xp[2], x3 = xp[3];
        float cc[2];
        #pragma unroll
        for (int c = 0; c < 2; ++c) {
            cc[c] = fabsf(x0.x - yc[c][0].x) + fabsf(x0.y - yc[c][0].y)
                  + fabsf(x0.z - yc[c][0].z) + fabsf(x0.w - yc[c][0].w)
                  + fabsf(x1.x - yc[c][1].x) + fabsf(x1.y - yc[c][1].y)
                  + fabsf(x1.z - yc[c][1].z) + fabsf(x1.w - yc[c][1].w)
                  + fabsf(x2.x - yc[c][2].x) + fabsf(x2.y - yc[c][2].y)
                  + fabsf(x2.z - yc[c][2].z) + fabsf(x2.w - yc[c][2].w)
                  + fabsf(x3.x - yc[c][3].x) + fabsf(x3.y - yc[c][3].y)
                  + fabsf(x3.z - yc[c][3].z) + fabsf(x3.w - yc[c][3].w);
        }
        c2[k] = make_float2(cc[0], cc[1]);
    }

    float u_loc[2], lmu[2], lnu[2];
    #pragma unroll
    for (int rr = 0; rr < 2; ++rr) {
        u_loc[rr] = 0.f;
        lmu[rr] = __logf(wx[n * PP + i0 + 2 * w + rr] + 1e-8f);
        lnu[rr] = __logf(wy[n * PP + i0 + 2 * w + rr] + 1e-8f);
    }

    // ---------------- Sinkhorn loop: per-group sync, fixed 100 iterations ----------------
    unsigned lgen = 0;
    #pragma unroll 1
    for (int t = 0; t < MAXIT; ++t) {
        // u-phase: u_new[i] = eps*log_mu[i] - eps*LSE_j((v_j - C_ij)/eps)
        if (t == 0) {
            for (int idx = threadIdx.x; idx < PP; idx += NTHR) sbuf[idx] = 0.f;
        } else {
            const float* vs = sc + VSNAP_OFF + (size_t)(t - 1) * PP;
            for (int idx = threadIdx.x; idx < PP; idx += NTHR)
                sbuf[idx] = aload(vs + idx);
        }
        __syncthreads();

        float vv[16];
        #pragma unroll
        for (int k = 0; k < 16; ++k) vv[k] = sbuf[l + 64 * k];
        float werr = 0.f;
        #pragma unroll
        for (int rr = 0; rr < 2; ++rr) {
            int r = 2 * w + rr;
            float tt[16], m = -3.4e38f;
            #pragma unroll
            for (int k = 0; k < 16; ++k) {
                tt[k] = vv[k] - rt[r * PP + l + 64 * k];
                m = fmaxf(m, tt[k]);
            }
            #pragma unroll
            for (int off = 32; off >= 1; off >>= 1) m = fmaxf(m, __shfl_xor(m, off));
            float s = 0.f;
            #pragma unroll
            for (int k = 0; k < 16; ++k) s += __expf((tt[k] - m) * IEPS);
            #pragma unroll
            for (int off = 32; off >= 1; off >>= 1) s += __shfl_xor(s, off);
            float unew = EPSV * lmu[rr] - (m + EPSV * __logf(s));
            werr += fabsf(unew - u_loc[rr]);
            u_loc[rr] = unew;
            if (l == 0) astore(sc + (size_t)t * PP + i0 + r, unew);   // u_snap(t)
        }
        if (l == 0) atomicAdd(&e_ws[((size_t)n * MAXIT + t) * 8 + w], werr);

        ++lgen;
        barrier_wait(grp_cnt, grp_flags, 8, grp_myflag, GPB, lgen);  // u_snap(t) visible

        // v-phase: v_new[j] = eps*log_nu[j] - eps*LSE_i((u_i - C_ij)/eps)
        {
            const float* us = sc + (size_t)t * PP;
            for (int idx = threadIdx.x; idx < PP; idx += NTHR)
                sbuf[idx] = aload(us + idx);
        }
        __syncthreads();

        float uu[16];
        #pragma unroll
        for (int k = 0; k < 16; ++k) uu[k] = sbuf[l + 64 * k];
        #pragma unroll
        for (int c = 0; c < 2; ++c) {
            float tt[16], m = -3.4e38f;
            #pragma unroll
            for (int k = 0; k < 16; ++k) {
                tt[k] = uu[k] - (c ? c2[k].y : c2[k].x);
                m = fmaxf(m, tt[k]);
            }
            #pragma unroll
            for (int off = 32; off >= 1; off >>= 1) m = fmaxf(m, __shfl_xor(m, off));
            float s = 0.f;
            #pragma unroll
            for (int k = 0; k < 16; ++k) s += __expf((tt[k] - m) * IEPS);
            #pragma unroll
            for (int off = 32; off >= 1; off >>= 1) s += __shfl_xor(s, off);
            float vnew = EPSV * lnu[c] - (m + EPSV * __logf(s));
            if (l == 0) astore(sc + VSNAP_OFF + (size_t)t * PP + i0 + 2 * w + c, vnew);
        }

        ++lgen;
        barrier_wait(grp_cnt, grp_flags, 8, grp_myflag, GPB, lgen);  // v_snap(t) visible
    }

    // ---------------- global barrier: all groups done, all e_ws final ----------------
    barrier_wait(fin_cnt, fin_flags, 16, b >> 4, NBLK, 1u);

    // ---- T = first t with sum_n err_n(t) < NB*THRESH (else MAXIT-1) ----
    if (w == 0) {
        float s1 = 0.f;
        #pragma unroll
        for (int q = 0; q < NB; ++q)
            #pragma unroll
            for (int s = 0; s < 8; ++s)
                s1 += aload(&e_ws[((size_t)q * MAXIT + l) * 8 + s]);
        unsigned long long b1 = __ballot(s1 < THRESHV * (float)NB);
        bool c2v = false;
        if (64 + l < MAXIT) {
            float s2 = 0.f;
            #pragma unroll
            for (int q = 0; q < NB; ++q)
                #pragma unroll
                for (int s = 0; s < 8; ++s)
                    s2 += aload(&e_ws[((size_t)q * MAXIT + 64 + l) * 8 + s]);
            c2v = (s2 < THRESHV * (float)NB);
        }
        unsigned long long b2 = __ballot(c2v);
        int T = b1 ? (__ffsll((long long)b1) - 1)
                   : (b2 ? 64 + (__ffsll((long long)b2) - 1) : MAXIT - 1);
        if (threadIdx.x == 0) Ts = T;
    }
    __syncthreads();
    const int T = Ts;

    // ---- reload snapshot T: this block's 16 u values + full v ----
    #pragma unroll
    for (int rr = 0; rr < 2; ++rr)
        u_loc[rr] = aload(sc + (size_t)T * PP + i0 + 2 * w + rr);
    {
        const float* vs = sc + VSNAP_OFF + (size_t)T * PP;
        for (int idx = threadIdx.x; idx < PP; idx += NTHR)
            sbuf[idx] = aload(vs + idx);
    }
    // group barrier: all snapshot reads in this group done before C overwrites scratch
    ++lgen;
    barrier_wait(grp_cnt, grp_flags, 8, grp_myflag, GPB, lgen);

    // ---------------- epilogue: write C, pi, cost ----------------
    float cacc = 0.f;
    #pragma unroll
    for (int rr = 0; rr < 2; ++rr) {
        int r  = 2 * w + rr;
        int i  = i0 + r;
        float un = u_loc[rr];
        #pragma unroll
        for (int k = 0; k < 4; ++k) {
            int j = 256 * k + 4 * l;
            float4 c4 = *(const float4*)&rt[r * PP + j];
            float4 v4 = *(const float4*)&sbuf[j];
            float4 p4;
            p4.x = __expf((un + v4.x - c4.x) * IEPS);
            p4.y = __expf((un + v4.y - c4.y) * IEPS);
            p4.z = __expf((un + v4.z - c4.z) * IEPS);
            p4.w = __expf((un + v4.w - c4.w) * IEPS);
            *(float4*)&out_pi[((size_t)n * PP + i) * PP + j] = p4;
            *(float4*)&out_C [((size_t)n * PP + i) * PP + j] = c4;
            cacc += p4.x * c4.x + p4.y * c4.y + p4.z * c4.z + p4.w * c4.w;
        }
    }
    #pragma unroll
    for (int off = 32; off >= 1; off >>= 1) cacc += __shfl_xor(cacc, off);
    if (l == 0) cred[w] = cacc;
    __syncthreads();
    if (threadIdx.x == 0) {
        float s = 0.f;
        #pragma unroll
        for (int q = 0; q < 8; ++q) s += cred[q];
        atomicAdd(&out_cost[n], s);   // out_cost zeroed by memset
    }
}

extern "C" void kernel_launch(void* const* d_in, const int* in_sizes, int n_in,
                              void* d_out, int out_size, void* d_ws, size_t ws_size,
                              hipStream_t stream) {
    const float* x  = (const float*)d_in[0];
    const float* y  = (const float*)d_in[1];
    const float* wx = (const float*)d_in[2];
    const float* wy = (const float*)d_in[3];
    float* out = (float*)d_out;
    float* ws  = (float*)d_ws;

    hipMemsetAsync(d_ws, 0, WS_BYTES, stream);            // barriers + err slots
    hipMemsetAsync(d_out, 0, NB * sizeof(float), stream); // cost accumulators

    hipLaunchKernelGGL(sinkhorn_kernel, dim3(NBLK), dim3(NTHR), 0, stream,
                       x, y, wx, wy, out, ws);
}

// Round 6
// 792.467 us; speedup vs baseline: 5.3900x; 1.9762x over previous
//
#include <hip/hip_runtime.h>

static constexpr int   NB      = 4;     // batches
static constexpr int   PP      = 1024;  // points per side
static constexpr int   DD      = 16;    // feature dim
static constexpr float EPSV    = 0.1f;
static constexpr float KE      = 14.42695041f;   // (1/eps) * log2(e)  (exp2 arg scale)
static constexpr float KL      = 0.0693147181f;  // eps * ln(2)        (log2 result scale)
static constexpr int   MAXIT   = 100;
static constexpr float THRESHV = 0.1f;

static constexpr int NBLK = 256;   // 64 blocks per batch group, all co-resident
static constexpr int NTHR = 512;   // 8 waves

// fast base-2 HW transcendentals (v_exp_f32 = 2^x, v_log_f32 = log2 x)
__device__ __forceinline__ float fexp2(float v) { return __builtin_amdgcn_exp2f(v); }
__device__ __forceinline__ float flog2(float v) { return __builtin_amdgcn_logf(v); }

// ws u32 layout: arrival slot for block b at ws32[b*16] (64 B apart); Tslot at ws32[4096]
static constexpr size_t WS_BYTES = (4096 + 16) * 4;

// out_C scratch layout per batch (sc = out_C + n*PP*PP), valid until epilogue:
//   u_snap(t) = sc + t*PP                  (rows   0..99)
//   v_snap(t) = sc + 131072 + t*PP         (rows 128..227)
//   err(t,g)  = sc + 262144 + t*64 + g     (rows 256..262)
static constexpr int VSNAP_OFF = 131072;
static constexpr int ERR_OFF   = 262144;

__device__ __forceinline__ float aload(const float* p) {
    return __hip_atomic_load(p, __ATOMIC_RELAXED, __HIP_MEMORY_SCOPE_AGENT);
}
__device__ __forceinline__ void astore(float* p, float v) {
    __hip_atomic_store(p, v, __ATOMIC_RELAXED, __HIP_MEMORY_SCOPE_AGENT);
}
__device__ __forceinline__ unsigned aloadu(const unsigned* p) {
    return __hip_atomic_load(p, __ATOMIC_RELAXED, __HIP_MEMORY_SCOPE_AGENT);
}
__device__ __forceinline__ void astoreu(unsigned* p, unsigned v) {
    __hip_atomic_store(p, v, __ATOMIC_RELAXED, __HIP_MEMORY_SCOPE_AGENT);
}
__device__ __forceinline__ float2 aload2(const float* p) {
    unsigned long long v = __hip_atomic_load((const unsigned long long*)p,
                                             __ATOMIC_RELAXED, __HIP_MEMORY_SCOPE_AGENT);
    union { unsigned long long u; float f[2]; } c; c.u = v;
    return make_float2(c.f[0], c.f[1]);
}
__device__ __forceinline__ void astore2(float* p, float a, float b) {
    union { unsigned long long u; float f[2]; } c; c.f[0] = a; c.f[1] = b;
    __hip_atomic_store((unsigned long long*)p, c.u,
                       __ATOMIC_RELAXED, __HIP_MEMORY_SCOPE_AGENT);
}

// Store+ballot-poll barrier: no atomics, no notify hop.
// Data contract (proven R3/R4): inter-block data moves via agent-scope relaxed
// atomics (write-through); __syncthreads() drains vmcnt before s_barrier, so all
// of a block's data stores are at the coherence point before its arrival store.
__device__ __forceinline__ void gbar_group(unsigned* ws32, int n, int g, unsigned gen) {
    __syncthreads();
    if (threadIdx.x < 64) {
        if (threadIdx.x == 0) astoreu(ws32 + (n * 64 + g) * 16, gen);
        const unsigned* sp = ws32 + (n * 64 + threadIdx.x) * 16;
        while (__ballot(aloadu(sp) >= gen) != ~0ull)
            __builtin_amdgcn_s_sleep(1);
    }
    __syncthreads();
}
__device__ __forceinline__ void gbar_all(unsigned* ws32, int b, unsigned gen) {
    __syncthreads();
    if (threadIdx.x < 64) {
        if (threadIdx.x == 0) astoreu(ws32 + b * 16, gen);
        for (;;) {
            bool ok = true;
            #pragma unroll
            for (int q = 0; q < 4; ++q)
                ok &= (aloadu(ws32 + (q * 64 + threadIdx.x) * 16) >= gen);
            if (__ballot(ok) == ~0ull) break;
            __builtin_amdgcn_s_sleep(1);
        }
    }
    __syncthreads();
}

__global__ __launch_bounds__(NTHR, 2)
void sinkhorn_kernel(const float* __restrict__ x, const float* __restrict__ y,
                     const float* __restrict__ wx, const float* __restrict__ wy,
                     float* __restrict__ out, float* __restrict__ ws)
{
    __shared__ float rt[16 * PP];    // this block's 16 C-rows (64 KB), live whole kernel
    __shared__ float sbuf[PP];       // u/v broadcast buffer (4 KB)
    __shared__ float cred[8];        // per-wave partials
    __shared__ int   Ts;             // chosen iteration T

    unsigned* ws32 = (unsigned*)ws;
    unsigned* Tslot = ws32 + 4096;

    float* out_cost = out;
    float* out_pi   = out + NB;
    float* out_C    = out + NB + (size_t)NB * PP * PP;

    const int b   = blockIdx.x;
    const int n   = b >> 6;            // batch / group
    const int g   = b & 63;            // block within group
    const int i0  = g * 16;            // first row (and col) of this block
    const int w   = threadIdx.x >> 6;  // wave 0..7
    const int l   = threadIdx.x & 63;  // lane
    const int tid = threadIdx.x;

    float* sc  = out_C + (size_t)n * PP * PP;   // this batch's snapshot scratch
    float* esc = sc + ERR_OFF;

    // ---------------- stage A: 16 C-rows -> LDS ----------------
    float4 xr[2][4];
    #pragma unroll
    for (int rr = 0; rr < 2; ++rr) {
        const float4* xp = (const float4*)(x + ((size_t)n * PP + (i0 + 2 * w + rr)) * DD);
        #pragma unroll
        for (int q = 0; q < 4; ++q) xr[rr][q] = xp[q];
    }
    #pragma unroll 4
    for (int k = 0; k < 16; ++k) {
        int j = l + 64 * k;
        const float4* yp = (const float4*)(y + ((size_t)n * PP + j) * DD);
        float4 y0 = yp[0], y1 = yp[1], y2 = yp[2], y3 = yp[3];
        #pragma unroll
        for (int rr = 0; rr < 2; ++rr) {
            float c = fabsf(xr[rr][0].x - y0.x) + fabsf(xr[rr][0].y - y0.y)
                    + fabsf(xr[rr][0].z - y0.z) + fabsf(xr[rr][0].w - y0.w)
                    + fabsf(xr[rr][1].x - y1.x) + fabsf(xr[rr][1].y - y1.y)
                    + fabsf(xr[rr][1].z - y1.z) + fabsf(xr[rr][1].w - y1.w)
                    + fabsf(xr[rr][2].x - y2.x) + fabsf(xr[rr][2].y - y2.y)
                    + fabsf(xr[rr][2].z - y2.z) + fabsf(xr[rr][2].w - y2.w)
                    + fabsf(xr[rr][3].x - y3.x) + fabsf(xr[rr][3].y - y3.y)
                    + fabsf(xr[rr][3].z - y3.z) + fabsf(xr[rr][3].w - y3.w);
            rt[(2 * w + rr) * PP + j] = c;
        }
    }

    // ---------------- stage B: 16 C-cols recomputed into registers ----------------
    float4 yc[2][4];
    #pragma unroll
    for (int c = 0; c < 2; ++c) {
        const float4* yp = (const float4*)(y + ((size_t)n * PP + (i0 + 2 * w + c)) * DD);
        #pragma unroll
        for (int q = 0; q < 4; ++q) yc[c][q] = yp[q];
    }
    float2 c2[16];
    #pragma unroll 4
    for (int k = 0; k < 16; ++k) {
        const float4* xp = (const float4*)(x + ((size_t)n * PP + (l + 64 * k)) * DD);
        float4 x0 = xp[0], x1 = xp[1], x2 = xp[2], x3 = xp[3];
        float cc[2];
        #pragma unroll
        for (int c = 0; c < 2; ++c) {
            cc[c] = fabsf(x0.x - yc[c][0].x) + fabsf(x0.y - yc[c][0].y)
                  + fabsf(x0.z - yc[c][0].z) + fabsf(x0.w - yc[c][0].w)
                  + fabsf(x1.x - yc[c][1].x) + fabsf(x1.y - yc[c][1].y)
                  + fabsf(x1.z - yc[c][1].z) + fabsf(x1.w - yc[c][1].w)
                  + fabsf(x2.x - yc[c][2].x) + fabsf(x2.y - yc[c][2].y)
                  + fabsf(x2.z - yc[c][2].z) + fabsf(x2.w - yc[c][2].w)
                  + fabsf(x3.x - yc[c][3].x) + fabsf(x3.y - yc[c][3].y)
                  + fabsf(x3.z - yc[c][3].z) + fabsf(x3.w - yc[c][3].w);
        }
        c2[k] = make_float2(cc[0], cc[1]);
    }

    float u_loc[2], lmu[2], lnu[2];
    #pragma unroll
    for (int rr = 0; rr < 2; ++rr) {
        u_loc[rr] = 0.f;
        lmu[rr] = __logf(wx[n * PP + i0 + 2 * w + rr] + 1e-8f);
        lnu[rr] = __logf(wy[n * PP + i0 + 2 * w + rr] + 1e-8f);
    }

    // ---------------- Sinkhorn loop: fixed 100 iters, per-group barriers ----------------
    // Freeze semantics: snapshots (u_{t+1}, v_{t+1}) + err_t per t; after the loop
    // T = first t with sum_n err_n(t) < NB*THRESH (exactly the reference's frozen state).
    #pragma unroll 1
    for (int t = 0; t < MAXIT; ++t) {
        // ---- u-phase: u_{t+1}[i] = eps*log_mu[i] - eps*LSE_j((v_t[j] - C_ij)/eps)
        if (t == 0) {
            sbuf[2 * tid] = 0.f; sbuf[2 * tid + 1] = 0.f;
        } else {
            float2 vp = aload2(sc + VSNAP_OFF + (size_t)(t - 1) * PP + 2 * tid);
            sbuf[2 * tid] = vp.x; sbuf[2 * tid + 1] = vp.y;
        }
        __syncthreads();

        float unew[2], werr;
        {
            float4 tt[2][4];
            float m0 = -3.4e38f, m1 = -3.4e38f;
            #pragma unroll
            for (int k = 0; k < 4; ++k) {
                int j = 256 * k + 4 * l;
                float4 v4 = *(const float4*)&sbuf[j];
                float4 ca = *(const float4*)&rt[(2 * w) * PP + j];
                float4 cb = *(const float4*)&rt[(2 * w + 1) * PP + j];
                tt[0][k] = make_float4(v4.x - ca.x, v4.y - ca.y, v4.z - ca.z, v4.w - ca.w);
                tt[1][k] = make_float4(v4.x - cb.x, v4.y - cb.y, v4.z - cb.z, v4.w - cb.w);
                m0 = fmaxf(m0, fmaxf(fmaxf(tt[0][k].x, tt[0][k].y), fmaxf(tt[0][k].z, tt[0][k].w)));
                m1 = fmaxf(m1, fmaxf(fmaxf(tt[1][k].x, tt[1][k].y), fmaxf(tt[1][k].z, tt[1][k].w)));
            }
            #pragma unroll
            for (int off = 32; off >= 1; off >>= 1) {
                m0 = fmaxf(m0, __shfl_xor(m0, off));
                m1 = fmaxf(m1, __shfl_xor(m1, off));
            }
            float s0 = 0.f, s1 = 0.f;
            #pragma unroll
            for (int k = 0; k < 4; ++k) {
                s0 += fexp2((tt[0][k].x - m0) * KE) + fexp2((tt[0][k].y - m0) * KE)
                    + fexp2((tt[0][k].z - m0) * KE) + fexp2((tt[0][k].w - m0) * KE);
                s1 += fexp2((tt[1][k].x - m1) * KE) + fexp2((tt[1][k].y - m1) * KE)
                    + fexp2((tt[1][k].z - m1) * KE) + fexp2((tt[1][k].w - m1) * KE);
            }
            #pragma unroll
            for (int off = 32; off >= 1; off >>= 1) {
                s0 += __shfl_xor(s0, off);
                s1 += __shfl_xor(s1, off);
            }
            unew[0] = EPSV * lmu[0] - (m0 + KL * flog2(s0));
            unew[1] = EPSV * lmu[1] - (m1 + KL * flog2(s1));
            werr = fabsf(unew[0] - u_loc[0]) + fabsf(unew[1] - u_loc[1]);
            u_loc[0] = unew[0]; u_loc[1] = unew[1];
            if (l == 0) {
                astore2(sc + (size_t)t * PP + i0 + 2 * w, unew[0], unew[1]);
                cred[w] = werr;
            }
        }

        // barrier (u_snap + err): err store folded into wave0 pre-arrival
        __syncthreads();                       // cred visible; all data stores drained
        if (tid < 64) {
            if (tid == 0) {
                float es = cred[0] + cred[1] + cred[2] + cred[3]
                         + cred[4] + cred[5] + cred[6] + cred[7];
                astore(esc + t * 64 + g, es);  // read only after final barrier (drain-ordered)
                astoreu(ws32 + (n * 64 + g) * 16, (unsigned)(2 * t + 1));
            }
            const unsigned* sp = ws32 + (n * 64 + tid) * 16;
            while (__ballot(aloadu(sp) >= (unsigned)(2 * t + 1)) != ~0ull)
                __builtin_amdgcn_s_sleep(1);
        }
        __syncthreads();

        // ---- v-phase: v_{t+1}[j] = eps*log_nu[j] - eps*LSE_i((u_{t+1}[i] - C_ij)/eps)
        {
            float2 up = aload2(sc + (size_t)t * PP + 2 * tid);
            sbuf[2 * tid] = up.x; sbuf[2 * tid + 1] = up.y;
        }
        __syncthreads();

        float vnew[2];
        {
            float tt0[16], tt1[16], m0 = -3.4e38f, m1 = -3.4e38f;
            #pragma unroll
            for (int k = 0; k < 16; ++k) {
                float uu = sbuf[l + 64 * k];
                tt0[k] = uu - c2[k].x;
                tt1[k] = uu - c2[k].y;
                m0 = fmaxf(m0, tt0[k]);
                m1 = fmaxf(m1, tt1[k]);
            }
            #pragma unroll
            for (int off = 32; off >= 1; off >>= 1) {
                m0 = fmaxf(m0, __shfl_xor(m0, off));
                m1 = fmaxf(m1, __shfl_xor(m1, off));
            }
            float s0 = 0.f, s1 = 0.f;
            #pragma unroll
            for (int k = 0; k < 16; ++k) {
                s0 += fexp2((tt0[k] - m0) * KE);
                s1 += fexp2((tt1[k] - m1) * KE);
            }
            #pragma unroll
            for (int off = 32; off >= 1; off >>= 1) {
                s0 += __shfl_xor(s0, off);
                s1 += __shfl_xor(s1, off);
            }
            vnew[0] = EPSV * lnu[0] - (m0 + KL * flog2(s0));
            vnew[1] = EPSV * lnu[1] - (m1 + KL * flog2(s1));
            if (l == 0)
                astore2(sc + VSNAP_OFF + (size_t)t * PP + i0 + 2 * w, vnew[0], vnew[1]);
        }

        gbar_group(ws32, n, g, (unsigned)(2 * t + 2));   // v_snap(t) visible
    }

    // ---------------- final: pick T, then epilogue ----------------
    gbar_all(ws32, b, (unsigned)(2 * MAXIT + 1));        // all err slots final

    if (b == 0 && tid < 64) {
        // lane l evaluates candidate t=l and t=64+l
        float s1 = 0.f;
        #pragma unroll 1
        for (int q = 0; q < NB; ++q) {
            const float* ebase = out_C + (size_t)q * PP * PP + ERR_OFF + l * 64;
            #pragma unroll
            for (int k = 0; k < 32; ++k) { float2 e2 = aload2(ebase + 2 * k); s1 += e2.x + e2.y; }
        }
        unsigned long long b1 = __ballot(s1 < THRESHV * (float)NB);
        float s2 = 1e30f;
        if (64 + l < MAXIT) {
            s2 = 0.f;
            #pragma unroll 1
            for (int q = 0; q < NB; ++q) {
                const float* ebase = out_C + (size_t)q * PP * PP + ERR_OFF + (64 + l) * 64;
                #pragma unroll
                for (int k = 0; k < 32; ++k) { float2 e2 = aload2(ebase + 2 * k); s2 += e2.x + e2.y; }
            }
        }
        unsigned long long b2 = __ballot(s2 < THRESHV * (float)NB);
        int T = b1 ? (__ffsll((long long)b1) - 1)
                   : (b2 ? 64 + (__ffsll((long long)b2) - 1) : MAXIT - 1);
        if (tid == 0) astoreu(Tslot, (unsigned)(T + 1));
    }
    if (tid == 0) {
        unsigned tv;
        while ((tv = aloadu(Tslot)) == 0u) __builtin_amdgcn_s_sleep(4);
        Ts = (int)tv - 1;
    }
    __syncthreads();
    const int T = Ts;

    // reload snapshot T: own u pair (all lanes load same 8B -> broadcast) + full v
    {
        float2 up = aload2(sc + (size_t)T * PP + i0 + 2 * w);
        u_loc[0] = up.x; u_loc[1] = up.y;
        float2 vp = aload2(sc + VSNAP_OFF + (size_t)T * PP + 2 * tid);
        sbuf[2 * tid] = vp.x; sbuf[2 * tid + 1] = vp.y;
    }
    // group's snapshot reads done before C overwrites the scratch region
    gbar_group(ws32, n, g, (unsigned)(2 * MAXIT + 2));

    // ---------------- epilogue: write C, pi, cost ----------------
    float cacc = 0.f;
    #pragma unroll
    for (int rr = 0; rr < 2; ++rr) {
        int r = 2 * w + rr;
        int i = i0 + r;
        float un = u_loc[rr];
        #pragma unroll
        for (int k = 0; k < 4; ++k) {
            int j = 256 * k + 4 * l;
            float4 c4 = *(const float4*)&rt[r * PP + j];
            float4 v4 = *(const float4*)&sbuf[j];
            float4 p4;
            p4.x = fexp2((un + v4.x - c4.x) * KE);
            p4.y = fexp2((un + v4.y - c4.y) * KE);
            p4.z = fexp2((un + v4.z - c4.z) * KE);
            p4.w = fexp2((un + v4.w - c4.w) * KE);
            *(float4*)&out_pi[((size_t)n * PP + i) * PP + j] = p4;
            *(float4*)&out_C [((size_t)n * PP + i) * PP + j] = c4;
            cacc += p4.x * c4.x + p4.y * c4.y + p4.z * c4.z + p4.w * c4.w;
        }
    }
    #pragma unroll
    for (int off = 32; off >= 1; off >>= 1) cacc += __shfl_xor(cacc, off);
    if (l == 0) cred[w] = cacc;
    __syncthreads();
    if (tid == 0) {
        float s = 0.f;
        #pragma unroll
        for (int q = 0; q < 8; ++q) s += cred[q];
        atomicAdd(&out_cost[n], s);   // out_cost zeroed by memset
    }
}

extern "C" void kernel_launch(void* const* d_in, const int* in_sizes, int n_in,
                              void* d_out, int out_size, void* d_ws, size_t ws_size,
                              hipStream_t stream) {
    const float* x  = (const float*)d_in[0];
    const float* y  = (const float*)d_in[1];
    const float* wx = (const float*)d_in[2];
    const float* wy = (const float*)d_in[3];
    float* out = (float*)d_out;
    float* ws  = (float*)d_ws;

    (void)hipMemsetAsync(d_ws, 0, WS_BYTES, stream);            // barrier slots + Tslot
    (void)hipMemsetAsync(d_out, 0, NB * sizeof(float), stream); // cost accumulators

    hipLaunchKernelGGL(sinkhorn_kernel, dim3(NBLK), dim3(NTHR), 0, stream,
                       x, y, wx, wy, out, ws);
}

// Round 8
// 787.266 us; speedup vs baseline: 5.4256x; 1.0066x over previous
//
#include <hip/hip_runtime.h>

static constexpr int   NB      = 4;     // batches
static constexpr int   PP      = 1024;  // points per side
static constexpr int   DD      = 16;    // feature dim
static constexpr float EPSV    = 0.1f;
static constexpr float KE      = 14.42695041f;   // (1/eps) * log2(e)
static constexpr float KL      = 0.0693147181f;  // eps * ln(2)
static constexpr int   MAXIT   = 100;
static constexpr float THRESHV = 0.1f;

static constexpr int NBLK = 256;   // 64 blocks per batch group, all co-resident
static constexpr int NTHR = 512;   // 8 waves
static constexpr unsigned DONEG = 1000000u;   // "group finished" slot gen

// fast base-2 HW transcendentals (v_exp_f32 = 2^x, v_log_f32 = log2 x)
__device__ __forceinline__ float fexp2(float v) { return __builtin_amdgcn_exp2f(v); }
__device__ __forceinline__ float flog2(float v) { return __builtin_amdgcn_logf(v); }

// ws layout (u32 idx) — R6-PROVEN 64B-stride arrival slots:
//   slot(block b)     : ws32[b*16]          [0..4095]
//   Tslot             : ws32[4096]
//   exitf[n]          : ws32[4104+n]        (set-once, value = t_detect+1)
//   err_ws (floats)   : ws f-idx 4352 + n*128 + t   (pre-poisoned 0x7f = 3.4e38)
static constexpr int    ERR_F_OFF     = 4352;
static constexpr size_t WS_ZERO_BYTES = 4352 * 4;   // slots + Tslot + flags
static constexpr size_t ERR_BYTES    = 512 * 4;

// out_C scratch per batch (sc = out_C + n*PP*PP), valid until epilogue:
//   u_snap(t) = sc + t*PP ; v_snap(t) = sc + 131072 + t*PP
static constexpr int VSNAP_OFF = 131072;

__device__ __forceinline__ float aload(const float* p) {
    return __hip_atomic_load(p, __ATOMIC_RELAXED, __HIP_MEMORY_SCOPE_AGENT);
}
__device__ __forceinline__ void astore(float* p, float v) {
    __hip_atomic_store(p, v, __ATOMIC_RELAXED, __HIP_MEMORY_SCOPE_AGENT);
}
__device__ __forceinline__ unsigned aloadu(const unsigned* p) {
    return __hip_atomic_load(p, __ATOMIC_RELAXED, __HIP_MEMORY_SCOPE_AGENT);
}
__device__ __forceinline__ void astoreu(unsigned* p, unsigned v) {
    __hip_atomic_store(p, v, __ATOMIC_RELAXED, __HIP_MEMORY_SCOPE_AGENT);
}
__device__ __forceinline__ float2 aload2(const float* p) {
    unsigned long long v = __hip_atomic_load((const unsigned long long*)p,
                                             __ATOMIC_RELAXED, __HIP_MEMORY_SCOPE_AGENT);
    union { unsigned long long u; float f[2]; } c; c.u = v;
    return make_float2(c.f[0], c.f[1]);
}
__device__ __forceinline__ void astore2(float* p, float a, float b) {
    union { unsigned long long u; float f[2]; } c; c.f[0] = a; c.f[1] = b;
    __hip_atomic_store((unsigned long long*)p, c.u,
                       __ATOMIC_RELAXED, __HIP_MEMORY_SCOPE_AGENT);
}

// R6-proven store+ballot-poll barrier (64B-stride slots). Contract: all
// inter-block data is written with agent-scope relaxed atomics; __syncthreads
// drains vmcnt before s_barrier, so a block's data stores are at the coherence
// point before its arrival store.
__device__ __forceinline__ void gbar_group(unsigned* ws32, int n, int g, unsigned gen) {
    __syncthreads();
    if (threadIdx.x < 64) {
        if (threadIdx.x == 0) astoreu(ws32 + (n * 64 + g) * 16, gen);
        const unsigned* sp = ws32 + (n * 64 + threadIdx.x) * 16;
        while (__ballot(aloadu(sp) >= gen) != ~0ull)
            __builtin_amdgcn_s_sleep(1);
    }
    __syncthreads();
}

__global__ __launch_bounds__(NTHR, 2)
void sinkhorn_kernel(const float* __restrict__ x, const float* __restrict__ y,
                     const float* __restrict__ wx, const float* __restrict__ wy,
                     float* __restrict__ out, float* __restrict__ ws)
{
    __shared__ float rt[16 * PP];    // this block's 16 C-rows (64 KB)
    __shared__ float sbuf[PP];       // u/v broadcast buffer (4 KB)
    __shared__ float cred[8];        // per-wave partials (err, then cost)
    __shared__ int   Ts;             // chosen iteration T

    unsigned* ws32  = (unsigned*)ws;
    unsigned* Tslot = ws32 + 4096;
    unsigned* exitf = ws32 + 4104;
    float*    ews   = ws + ERR_F_OFF;

    float* out_cost = out;
    float* out_pi   = out + NB;
    float* out_C    = out + NB + (size_t)NB * PP * PP;

    const int b   = blockIdx.x;
    const int n   = b >> 6;            // batch / group
    const int g   = b & 63;            // block within group
    const int i0  = g * 16;            // first row (and col) of this block
    const int w   = threadIdx.x >> 6;  // wave 0..7
    const int l   = threadIdx.x & 63;  // lane
    const int tid = threadIdx.x;

    float* sc = out_C + (size_t)n * PP * PP;   // this batch's snapshot scratch

    // ---------------- stage A: 16 C-rows -> LDS ----------------
    float4 xr[2][4];
    #pragma unroll
    for (int rr = 0; rr < 2; ++rr) {
        const float4* xp = (const float4*)(x + ((size_t)n * PP + (i0 + 2 * w + rr)) * DD);
        #pragma unroll
        for (int q = 0; q < 4; ++q) xr[rr][q] = xp[q];
    }
    #pragma unroll 4
    for (int k = 0; k < 16; ++k) {
        int j = l + 64 * k;
        const float4* yp = (const float4*)(y + ((size_t)n * PP + j) * DD);
        float4 y0 = yp[0], y1 = yp[1], y2 = yp[2], y3 = yp[3];
        #pragma unroll
        for (int rr = 0; rr < 2; ++rr) {
            float c = fabsf(xr[rr][0].x - y0.x) + fabsf(xr[rr][0].y - y0.y)
                    + fabsf(xr[rr][0].z - y0.z) + fabsf(xr[rr][0].w - y0.w)
                    + fabsf(xr[rr][1].x - y1.x) + fabsf(xr[rr][1].y - y1.y)
                    + fabsf(xr[rr][1].z - y1.z) + fabsf(xr[rr][1].w - y1.w)
                    + fabsf(xr[rr][2].x - y2.x) + fabsf(xr[rr][2].y - y2.y)
                    + fabsf(xr[rr][2].z - y2.z) + fabsf(xr[rr][2].w - y2.w)
                    + fabsf(xr[rr][3].x - y3.x) + fabsf(xr[rr][3].y - y3.y)
                    + fabsf(xr[rr][3].z - y3.z) + fabsf(xr[rr][3].w - y3.w);
            rt[(2 * w + rr) * PP + j] = c;
        }
    }

    // ---------------- stage B: 16 C-cols recomputed into registers ----------------
    float4 yc[2][4];
    #pragma unroll
    for (int c = 0; c < 2; ++c) {
        const float4* yp = (const float4*)(y + ((size_t)n * PP + (i0 + 2 * w + c)) * DD);
        #pragma unroll
        for (int q = 0; q < 4; ++q) yc[c][q] = yp[q];
    }
    float2 c2[16];
    #pragma unroll 4
    for (int k = 0; k < 16; ++k) {
        const float4* xp = (const float4*)(x + ((size_t)n * PP + (l + 64 * k)) * DD);
        float4 x0 = xp[0], x1 = xp[1], x2 = xp[2], x3 = xp[3];
        float cc[2];
        #pragma unroll
        for (int c = 0; c < 2; ++c) {
            cc[c] = fabsf(x0.x - yc[c][0].x) + fabsf(x0.y - yc[c][0].y)
                  + fabsf(x0.z - yc[c][0].z) + fabsf(x0.w - yc[c][0].w)
                  + fabsf(x1.x - yc[c][1].x) + fabsf(x1.y - yc[c][1].y)
                  + fabsf(x1.z - yc[c][1].z) + fabsf(x1.w - yc[c][1].w)
                  + fabsf(x2.x - yc[c][2].x) + fabsf(x2.y - yc[c][2].y)
                  + fabsf(x2.z - yc[c][2].z) + fabsf(x2.w - yc[c][2].w)
                  + fabsf(x3.x - yc[c][3].x) + fabsf(x3.y - yc[c][3].y)
                  + fabsf(x3.z - yc[c][3].z) + fabsf(x3.w - yc[c][3].w);
        }
        c2[k] = make_float2(cc[0], cc[1]);
    }

    float lmu[2], lnu[2];
    #pragma unroll
    for (int rr = 0; rr < 2; ++rr) {
        lmu[rr] = __logf(wx[n * PP + i0 + 2 * w + rr] + 1e-8f);
        lnu[rr] = __logf(wy[n * PP + i0 + 2 * w + rr] + 1e-8f);
    }

    // per-thread previous-u pair (indices 2*tid, 2*tid+1) for the err series
    float uprev0 = 0.f, uprev1 = 0.f;

    // ---------------- Sinkhorn loop (early-exit capable) ----------------
    #pragma unroll 1
    for (int t = 0; t < MAXIT; ++t) {
        // early-exit: flag set at t_set (v-phase) is drained before arrival(2*t_set+2);
        // every block crossed u-barrier(t_set+1) before reaching top t_set+2 -> uniform.
        if (t >= 2) {
            unsigned ef = aloadu(exitf + n);
            if (ef != 0u && t >= (int)ef + 1) break;
        }

        // ---- u-phase: u_{t+1}[i] = eps*log_mu[i] - eps*LSE_j((v_t[j] - C_ij)/eps)
        if (t == 0) {
            sbuf[2 * tid] = 0.f; sbuf[2 * tid + 1] = 0.f;
        } else {
            float2 vp = aload2(sc + VSNAP_OFF + (size_t)(t - 1) * PP + 2 * tid);
            sbuf[2 * tid] = vp.x; sbuf[2 * tid + 1] = vp.y;
        }
        __syncthreads();

        {
            float4 tt[2][4];
            float m0 = -3.4e38f, m1 = -3.4e38f;
            #pragma unroll
            for (int k = 0; k < 4; ++k) {
                int j = 256 * k + 4 * l;
                float4 v4 = *(const float4*)&sbuf[j];
                float4 ca = *(const float4*)&rt[(2 * w) * PP + j];
                float4 cb = *(const float4*)&rt[(2 * w + 1) * PP + j];
                tt[0][k] = make_float4(v4.x - ca.x, v4.y - ca.y, v4.z - ca.z, v4.w - ca.w);
                tt[1][k] = make_float4(v4.x - cb.x, v4.y - cb.y, v4.z - cb.z, v4.w - cb.w);
                m0 = fmaxf(m0, fmaxf(fmaxf(tt[0][k].x, tt[0][k].y), fmaxf(tt[0][k].z, tt[0][k].w)));
                m1 = fmaxf(m1, fmaxf(fmaxf(tt[1][k].x, tt[1][k].y), fmaxf(tt[1][k].z, tt[1][k].w)));
            }
            #pragma unroll
            for (int off = 32; off >= 1; off >>= 1) {
                m0 = fmaxf(m0, __shfl_xor(m0, off));
                m1 = fmaxf(m1, __shfl_xor(m1, off));
            }
            float s0 = 0.f, s1 = 0.f;
            #pragma unroll
            for (int k = 0; k < 4; ++k) {
                s0 += fexp2((tt[0][k].x - m0) * KE) + fexp2((tt[0][k].y - m0) * KE)
                    + fexp2((tt[0][k].z - m0) * KE) + fexp2((tt[0][k].w - m0) * KE);
                s1 += fexp2((tt[1][k].x - m1) * KE) + fexp2((tt[1][k].y - m1) * KE)
                    + fexp2((tt[1][k].z - m1) * KE) + fexp2((tt[1][k].w - m1) * KE);
            }
            #pragma unroll
            for (int off = 32; off >= 1; off >>= 1) {
                s0 += __shfl_xor(s0, off);
                s1 += __shfl_xor(s1, off);
            }
            float un0 = EPSV * lmu[0] - (m0 + KL * flog2(s0));
            float un1 = EPSV * lmu[1] - (m1 + KL * flog2(s1));
            if (l == 0) astore2(sc + (size_t)t * PP + i0 + 2 * w, un0, un1);
        }

        gbar_group(ws32, n, g, (unsigned)(2 * t + 1));   // u_snap(t) visible

        // ---- v-phase: load full u_{t+1}; per-thread err vs previous u pair
        {
            float2 up = aload2(sc + (size_t)t * PP + 2 * tid);
            sbuf[2 * tid] = up.x; sbuf[2 * tid + 1] = up.y;
            float we = fabsf(up.x - uprev0) + fabsf(up.y - uprev1);
            uprev0 = up.x; uprev1 = up.y;
            #pragma unroll
            for (int off = 32; off >= 1; off >>= 1) we += __shfl_xor(we, off);
            if (l == 0) cred[w] = we;
        }
        __syncthreads();

        {
            float tt0[16], tt1[16], m0 = -3.4e38f, m1 = -3.4e38f;
            #pragma unroll
            for (int k = 0; k < 16; ++k) {
                float uu = sbuf[l + 64 * k];
                tt0[k] = uu - c2[k].x;
                tt1[k] = uu - c2[k].y;
                m0 = fmaxf(m0, tt0[k]);
                m1 = fmaxf(m1, tt1[k]);
            }
            #pragma unroll
            for (int off = 32; off >= 1; off >>= 1) {
                m0 = fmaxf(m0, __shfl_xor(m0, off));
                m1 = fmaxf(m1, __shfl_xor(m1, off));
            }
            float s0 = 0.f, s1 = 0.f;
            #pragma unroll
            for (int k = 0; k < 16; ++k) {
                s0 += fexp2((tt0[k] - m0) * KE);
                s1 += fexp2((tt1[k] - m1) * KE);
            }
            #pragma unroll
            for (int off = 32; off >= 1; off >>= 1) {
                s0 += __shfl_xor(s0, off);
                s1 += __shfl_xor(s1, off);
            }
            float vn0 = EPSV * lnu[0] - (m0 + KL * flog2(s0));
            float vn1 = EPSV * lnu[1] - (m1 + KL * flog2(s1));
            if (l == 0)
                astore2(sc + VSNAP_OFF + (size_t)t * PP + i0 + 2 * w, vn0, vn1);
        }
        // deterministic batch err (fixed-order sum); stored before the barrier
        // -> drained before arrival(2t+2) -> visible whenever slot >= 2t+2.
        if (g == 0 && tid == 0) {
            float es = cred[0] + cred[1] + cred[2] + cred[3]
                     + cred[4] + cred[5] + cred[6] + cred[7];
            astore(ews + n * 128 + t, es);
        }

        // v-barrier + off-critical-path convergence detection (g==0 wave only)
        __syncthreads();
        if (tid < 64) {
            if (tid == 0) astoreu(ws32 + (n * 64 + g) * 16, (unsigned)(2 * t + 2));
            if (g == 0) {
                // lane l checks candidates t0=l and t0=64+l (unwritten slots = 3.4e38)
                float s1f = aload(ews + 0 * 128 + tid) + aload(ews + 1 * 128 + tid)
                          + aload(ews + 2 * 128 + tid) + aload(ews + 3 * 128 + tid);
                float s2f = aload(ews + 0 * 128 + 64 + tid) + aload(ews + 1 * 128 + 64 + tid)
                          + aload(ews + 2 * 128 + 64 + tid) + aload(ews + 3 * 128 + 64 + tid);
                unsigned long long bb = __ballot(s1f < THRESHV * (float)NB)
                                      | __ballot(s2f < THRESHV * (float)NB);
                if (bb != 0ull && tid == 0 && aloadu(exitf + n) == 0u)
                    astoreu(exitf + n, (unsigned)(t + 1));   // set-once
            }
            const unsigned* sp = ws32 + (n * 64 + tid) * 16;
            while (__ballot(aloadu(sp) >= (unsigned)(2 * t + 2)) != ~0ull)
                __builtin_amdgcn_s_sleep(1);
        }
        __syncthreads();
    }

    // ---------------- group-done signal, T-pick ----------------
    if (g == 0 && tid == 0) astoreu(ws32 + (n * 64) * 16, DONEG);

    if (b == 0 && tid < 64) {
        for (;;) {   // wait all 4 groups done (their err series final & drained)
            bool ok = (tid >= 4) || (aloadu(ws32 + tid * 64 * 16) >= DONEG);
            if (__ballot(ok) == ~0ull) break;
            __builtin_amdgcn_s_sleep(2);
        }
        float s1f = aload(ews + 0 * 128 + tid) + aload(ews + 1 * 128 + tid)
                  + aload(ews + 2 * 128 + tid) + aload(ews + 3 * 128 + tid);
        float s2f = aload(ews + 0 * 128 + 64 + tid) + aload(ews + 1 * 128 + 64 + tid)
                  + aload(ews + 2 * 128 + 64 + tid) + aload(ews + 3 * 128 + 64 + tid);
        unsigned long long b1 = __ballot(s1f < THRESHV * (float)NB);
        unsigned long long b2 = __ballot(s2f < THRESHV * (float)NB);
        int T = b1 ? (__ffsll((long long)b1) - 1)
                   : (b2 ? 64 + (__ffsll((long long)b2) - 1) : MAXIT - 1);
        if (tid == 0) astoreu(Tslot, (unsigned)(T + 1));
    }
    if (tid == 0) {
        unsigned tv;
        while ((tv = aloadu(Tslot)) == 0u) __builtin_amdgcn_s_sleep(2);
        Ts = (int)tv - 1;
    }
    __syncthreads();
    const int T = Ts;

    // reload snapshot T: own u pair (broadcast) + full v into sbuf
    float u_loc[2];
    {
        float2 up = aload2(sc + (size_t)T * PP + i0 + 2 * w);
        u_loc[0] = up.x; u_loc[1] = up.y;
        float2 vp = aload2(sc + VSNAP_OFF + (size_t)T * PP + 2 * tid);
        sbuf[2 * tid] = vp.x; sbuf[2 * tid + 1] = vp.y;
    }
    // group's snapshot reads done before C overwrites the scratch region
    gbar_group(ws32, n, g, DONEG + 1u);

    // ---------------- epilogue: write C, pi, cost ----------------
    float cacc = 0.f;
    #pragma unroll
    for (int rr = 0; rr < 2; ++rr) {
        int r = 2 * w + rr;
        int i = i0 + r;
        float un = u_loc[rr];
        #pragma unroll
        for (int k = 0; k < 4; ++k) {
            int j = 256 * k + 4 * l;
            float4 c4 = *(const float4*)&rt[r * PP + j];
            float4 v4 = *(const float4*)&sbuf[j];
            float4 p4;
            p4.x = fexp2((un + v4.x - c4.x) * KE);
            p4.y = fexp2((un + v4.y - c4.y) * KE);
            p4.z = fexp2((un + v4.z - c4.z) * KE);
            p4.w = fexp2((un + v4.w - c4.w) * KE);
            *(float4*)&out_pi[((size_t)n * PP + i) * PP + j] = p4;
            *(float4*)&out_C [((size_t)n * PP + i) * PP + j] = c4;
            cacc += p4.x * c4.x + p4.y * c4.y + p4.z * c4.z + p4.w * c4.w;
        }
    }
    #pragma unroll
    for (int off = 32; off >= 1; off >>= 1) cacc += __shfl_xor(cacc, off);
    if (l == 0) cred[w] = cacc;
    __syncthreads();
    if (tid == 0) {
        float s = 0.f;
        #pragma unroll
        for (int q = 0; q < 8; ++q) s += cred[q];
        atomicAdd(&out_cost[n], s);   // out_cost zeroed by memset
    }
}

extern "C" void kernel_launch(void* const* d_in, const int* in_sizes, int n_in,
                              void* d_out, int out_size, void* d_ws, size_t ws_size,
                              hipStream_t stream) {
    const float* x  = (const float*)d_in[0];
    const float* y  = (const float*)d_in[1];
    const float* wx = (const float*)d_in[2];
    const float* wy = (const float*)d_in[3];
    float* out = (float*)d_out;
    float* ws  = (float*)d_ws;

    (void)hipMemsetAsync(d_ws, 0, WS_ZERO_BYTES, stream);             // slots/Tslot/flags
    (void)hipMemsetAsync((char*)d_ws + WS_ZERO_BYTES, 0x7f, ERR_BYTES, stream); // err = 3.4e38
    (void)hipMemsetAsync(d_out, 0, NB * sizeof(float), stream);       // cost accumulators

    hipLaunchKernelGGL(sinkhorn_kernel, dim3(NBLK), dim3(NTHR), 0, stream,
                       x, y, wx, wy, out, ws);
}